// Round 1
// baseline (2217.080 us; speedup 1.0000x reference)
//
#include <hip/hip_runtime.h>
#include <hip/hip_fp16.h>
#include <math.h>

// Problem constants (from reference): B=16, N=16384, C_IN=C_OUT=128, K=9
#define B_ 16
#define N_ 16384
#define C_ 128
#define K_ 9
#define FCONV 1152          // K_*C_  (conv feature dim)
#define FTOT 1280           // FCONV + C_ (appended skip features = x row)
#define WCH 32              // f-chunk width for W staging
#define NCHUNK_CONV 36      // 1152/32
#define NCHUNK_SKIP 4       // 128/32
#define WPAD 34             // W_s row stride in halfs (32+2: odd*17 -> 2-way bank alias = free)

typedef _Float16 h2 __attribute__((ext_vector_type(2)));

__device__ __forceinline__ float dot2acc(h2 a, h2 b, float c) {
#if __has_builtin(__builtin_amdgcn_fdot2)
    return __builtin_amdgcn_fdot2(a, b, c, false);   // v_dot2_f32_f16, fp32 accum
#else
    return c + (float)a.x * (float)b.x + (float)a.y * (float)b.y;
#endif
}

__device__ __forceinline__ float elu_f(float v) {
    return v > 0.f ? v : expm1f(v);
}

__global__ __launch_bounds__(256) void paiconv_fused(
    const float* __restrict__ x,      // (B,N,C)
    const int*   __restrict__ idx,    // (N,K)
    const float* __restrict__ P,      // (N,K,K)
    const float* __restrict__ Wc,     // (C_OUT, K*C)
    const float* __restrict__ bc,     // (C_OUT)
    const float* __restrict__ Ws,     // (C_OUT, C)
    const float* __restrict__ bs,     // (C_OUT)
    float*       __restrict__ out)    // (B,N,C_OUT)
{
    __shared__ _Float16 flat_s[B_ * FTOT];   // 40960 B : flat[m][f] (f16), m = batch
    __shared__ _Float16 W_s[C_ * WPAD];      //  8704 B : staged W chunk
    __shared__ float    P_s[K_ * K_];
    __shared__ int      idx_s[K_];

    const int n   = blockIdx.x;
    const int tid = threadIdx.x;

    if (tid < K_ * K_) P_s[tid] = P[n * (K_ * K_) + tid];
    if (tid < K_)      idx_s[tid] = idx[n * K_ + tid];
    __syncthreads();

    // ---- phase 1: gather neighbours + P-mix + ELU -> flat_s[m][k*C+c]; x row -> flat_s[m][1152+c]
    {
        const int c  = tid & (C_ - 1);
        const int hh = tid >> 7;            // 0 or 1
        int id[K_];
        #pragma unroll
        for (int j = 0; j < K_; ++j) id[j] = idx_s[j];

        #pragma unroll
        for (int i = 0; i < 8; ++i) {
            const int m = hh * 8 + i;
            const float* xb = x + (size_t)m * N_ * C_ + c;
            float v[K_];
            #pragma unroll
            for (int j = 0; j < K_; ++j)
                v[j] = ((unsigned)id[j] < (unsigned)N_) ? xb[(size_t)id[j] * C_] : 0.f;
            #pragma unroll
            for (int k = 0; k < K_; ++k) {
                float s = 0.f;
                #pragma unroll
                for (int j = 0; j < K_; ++j) s = fmaf(P_s[k * K_ + j], v[j], s);
                flat_s[m * FTOT + k * C_ + c] = (_Float16)elu_f(s);
            }
            flat_s[m * FTOT + FCONV + c] = (_Float16)xb[(size_t)n * C_];
        }
    }

    const int o  = tid & (C_ - 1);
    const int hh = tid >> 7;
    float accC[8] = {0.f,0.f,0.f,0.f,0.f,0.f,0.f,0.f};
    float accS[8] = {0.f,0.f,0.f,0.f,0.f,0.f,0.f,0.f};

    // ---- phase 2a: conv GEMM, 36 chunks of 32 features ----
    for (int ch = 0; ch < NCHUNK_CONV; ++ch) {
        __syncthreads();
        // stage W_conv[:, ch*32 .. +32) as f16: 128 rows x 32 cols
        #pragma unroll
        for (int i = 0; i < 4; ++i) {
            const int l   = i * 256 + tid;        // 0..1023 float4 units
            const int row = l >> 3;               // 8 float4 per row
            const int c4  = (l & 7) << 2;
            const float4 w = *(const float4*)&Wc[(size_t)row * FCONV + ch * WCH + c4];
            _Float16* d = &W_s[row * WPAD + c4];
            d[0] = (_Float16)w.x; d[1] = (_Float16)w.y;
            d[2] = (_Float16)w.z; d[3] = (_Float16)w.w;
        }
        __syncthreads();
        const h2* wrow = (const h2*)&W_s[o * WPAD];
        #pragma unroll
        for (int p = 0; p < WCH / 2; ++p) {
            const h2 w2 = wrow[p];
            #pragma unroll
            for (int i = 0; i < 8; ++i) {
                const int m = hh * 8 + i;
                const h2 a2 = *(const h2*)&flat_s[m * FTOT + ch * WCH + p * 2];
                accC[i] = dot2acc(a2, w2, accC[i]);
            }
        }
    }

    // ---- phase 2b: skip GEMM, 4 chunks of 32 ----
    for (int ch = 0; ch < NCHUNK_SKIP; ++ch) {
        __syncthreads();
        #pragma unroll
        for (int i = 0; i < 4; ++i) {
            const int l   = i * 256 + tid;
            const int row = l >> 3;
            const int c4  = (l & 7) << 2;
            const float4 w = *(const float4*)&Ws[(size_t)row * C_ + ch * WCH + c4];
            _Float16* d = &W_s[row * WPAD + c4];
            d[0] = (_Float16)w.x; d[1] = (_Float16)w.y;
            d[2] = (_Float16)w.z; d[3] = (_Float16)w.w;
        }
        __syncthreads();
        const h2* wrow = (const h2*)&W_s[o * WPAD];
        #pragma unroll
        for (int p = 0; p < WCH / 2; ++p) {
            const h2 w2 = wrow[p];
            #pragma unroll
            for (int i = 0; i < 8; ++i) {
                const int m = hh * 8 + i;
                const h2 a2 = *(const h2*)&flat_s[m * FTOT + FCONV + ch * WCH + p * 2];
                accS[i] = dot2acc(a2, w2, accS[i]);
            }
        }
    }

    // ---- epilogue: out = elu(conv + b_conv) + skip + b_skip ----
    const float bcv = bc[o];
    const float bsv = bs[o];
    #pragma unroll
    for (int i = 0; i < 8; ++i) {
        const int m = hh * 8 + i;
        const float z = elu_f(accC[i] + bcv);
        out[((size_t)m * N_ + n) * C_ + o] = z + accS[i] + bsv;
    }
}

extern "C" void kernel_launch(void* const* d_in, const int* in_sizes, int n_in,
                              void* d_out, int out_size, void* d_ws, size_t ws_size,
                              hipStream_t stream) {
    const float* x   = (const float*)d_in[0];
    const int*   idx = (const int*)  d_in[1];
    const float* P   = (const float*)d_in[2];
    const float* Wc  = (const float*)d_in[3];
    const float* bc  = (const float*)d_in[4];
    const float* Ws  = (const float*)d_in[5];
    const float* bs  = (const float*)d_in[6];
    float* out = (float*)d_out;

    paiconv_fused<<<dim3(N_), dim3(256), 0, stream>>>(x, idx, P, Wc, bc, Ws, bs, out);
}

// Round 2
// 622.996 us; speedup vs baseline: 3.5587x; 3.5587x over previous
//
#include <hip/hip_runtime.h>
#include <hip/hip_fp16.h>
#include <math.h>

// B=16, N=16384, C_IN=C_OUT=128, K=9
#define B_ 16
#define N_ 16384
#define C_ 128
#define K_ 9
#define FCONV 1152           // K_*C_
#define G_ 2                 // nodes per block
#define FPAD 1160            // flat row stride in halfs (1152+8): 16B-aligned, 2-way bank alias (free)
#define LDS_BYTES (G_ * B_ * FPAD * 2)   // 74240 B dynamic LDS

typedef _Float16 half8 __attribute__((ext_vector_type(8)));
typedef float floatx4 __attribute__((ext_vector_type(4)));

__device__ __forceinline__ float elu_f(float v) {
    // fast ELU: exp(v)-1 for v<0 via v_exp_f32 (abs err ~1e-6, threshold is 0.136)
    return v > 0.f ? v : (__expf(v) - 1.f);
}

// Pre-swizzle W into MFMA b-fragment-major f16 layout in d_ws:
//  conv: frag index ((ot*36 + kc)*64 + lane), 8 halfs each; value = Wc[ot*16 + (lane&15)][kc*32 + (lane>>4)*8 + j]
//  skip: frag index ((ot*4 + kc)*64 + lane);               value = Ws[ot*16 + (lane&15)][kc*32 + (lane>>4)*8 + j]
__global__ void build_wfrag(const float* __restrict__ Wc, const float* __restrict__ Ws,
                            _Float16* __restrict__ WcF, _Float16* __restrict__ WsF) {
    const int i = blockIdx.x * 256 + threadIdx.x;
    if (i < 8 * 36 * 64 * 8) {
        const int j = i & 7, lane = (i >> 3) & 63;
        const int rest = i >> 9;               // ot*36 + kc
        const int kc = rest % 36, ot = rest / 36;
        WcF[i] = (_Float16)Wc[(size_t)(ot * 16 + (lane & 15)) * FCONV + kc * 32 + (lane >> 4) * 8 + j];
    }
    if (i < 8 * 4 * 64 * 8) {
        const int j = i & 7, lane = (i >> 3) & 63;
        const int rest = i >> 9;               // ot*4 + kc
        const int kc = rest & 3, ot = rest >> 2;
        WsF[i] = (_Float16)Ws[(size_t)(ot * 16 + (lane & 15)) * C_ + kc * 32 + (lane >> 4) * 8 + j];
    }
}

template <bool WF16>
__global__ __launch_bounds__(256) void paiconv_mfma(
    const float* __restrict__ x,      // (B,N,C)
    const int*   __restrict__ idx,    // (N,K)
    const float* __restrict__ P,      // (N,K,K)
    const void*  __restrict__ WcP,    // WF16: fragment-major f16; else fp32 row-major (C_OUT, K*C)
    const float* __restrict__ bc,
    const void*  __restrict__ WsP,    // WF16: fragment-major f16; else fp32 row-major (C_OUT, C)
    const float* __restrict__ bs,
    float*       __restrict__ out)    // (B,N,C_OUT)
{
    extern __shared__ _Float16 flat_s[];     // [G][16][FPAD] f16
    __shared__ float P_s[G_ * 81];
    __shared__ int   idx_s[G_ * K_];

    const int tid = threadIdx.x;
    const int n0  = blockIdx.x * G_;

    if (tid < G_ * 81) {
        const int g = tid / 81, t = tid - g * 81;
        P_s[tid] = P[(size_t)(n0 + g) * 81 + t];
    }
    if (tid < G_ * K_) {
        const int g = tid / K_, j = tid - g * K_;
        idx_s[tid] = idx[(size_t)(n0 + g) * K_ + j];
    }
    __syncthreads();

    // ---------------- phase 1: gather + P-mix + ELU -> flat_s (f16) ----------------
    {
        const int c = tid & (C_ - 1);
        const int h = tid >> 7;                 // 0/1 -> batches [0..8) / [8..16)
        for (int g = 0; g < G_; ++g) {
            int id[K_];
            #pragma unroll
            for (int j = 0; j < K_; ++j) id[j] = idx_s[g * K_ + j];
            const float* Pg = &P_s[g * 81];
            _Float16* fg = &flat_s[g * (B_ * FPAD)];

            // load all neighbour values first (72 outstanding coalesced loads)
            float v[8][K_];
            #pragma unroll
            for (int i = 0; i < 8; ++i) {
                const int m = h * 8 + i;
                const float* xb = x + (size_t)m * (N_ * C_) + c;
                #pragma unroll
                for (int j = 0; j < K_; ++j)
                    v[i][j] = ((unsigned)id[j] < (unsigned)N_) ? xb[(size_t)id[j] * C_] : 0.f;
            }
            // k-outer so the 9 P-row LDS reads are CSE'd across the 8 batches
            #pragma unroll
            for (int k = 0; k < K_; ++k) {
                float pr[K_];
                #pragma unroll
                for (int j = 0; j < K_; ++j) pr[j] = Pg[k * K_ + j];
                #pragma unroll
                for (int i = 0; i < 8; ++i) {
                    float s = 0.f;
                    #pragma unroll
                    for (int j = 0; j < K_; ++j) s = fmaf(pr[j], v[i][j], s);
                    fg[(h * 8 + i) * FPAD + k * C_ + c] = (_Float16)elu_f(s);
                }
            }
        }
    }
    __syncthreads();

    // ---------------- phase 2: MFMA GEMMs ----------------
    const int w    = tid >> 6;
    const int lane = tid & 63;
    const int col  = lane & 15;      // a-frag row m / b-frag col o / C-frag col
    const int quad = lane >> 4;      // 0..3
    const int o0   = w * 32;         // wave covers output cols [o0, o0+32): tiles ot = w*2, w*2+1

    floatx4 accC[G_][2], accS[G_][2];
    #pragma unroll
    for (int g = 0; g < G_; ++g)
        #pragma unroll
        for (int t = 0; t < 2; ++t) {
            accC[g][t] = (floatx4){0.f, 0.f, 0.f, 0.f};
            accS[g][t] = (floatx4){0.f, 0.f, 0.f, 0.f};
        }

    // conv GEMM: flat (M=16 x 1152) @ Wc^T -> 16x128, per node
    for (int k0 = 0; k0 < FCONV; k0 += 32) {
        half8 a[G_];
        #pragma unroll
        for (int g = 0; g < G_; ++g)
            a[g] = *(const half8*)&flat_s[g * (B_ * FPAD) + col * FPAD + k0 + quad * 8];
        #pragma unroll
        for (int t = 0; t < 2; ++t) {
            half8 b;
            if (WF16) {
                b = ((const half8*)WcP)[((w * 2 + t) * 36 + (k0 >> 5)) * 64 + lane];
            } else {
                const float* p = (const float*)WcP + (size_t)(o0 + t * 16 + col) * FCONV + k0 + quad * 8;
                const float4 w0 = *(const float4*)p;
                const float4 w1 = *(const float4*)(p + 4);
                b = (half8){(_Float16)w0.x, (_Float16)w0.y, (_Float16)w0.z, (_Float16)w0.w,
                            (_Float16)w1.x, (_Float16)w1.y, (_Float16)w1.z, (_Float16)w1.w};
            }
            #pragma unroll
            for (int g = 0; g < G_; ++g)
                accC[g][t] = __builtin_amdgcn_mfma_f32_16x16x32_f16(a[g], b, accC[g][t], 0, 0, 0);
        }
    }

    // skip GEMM: x-row (M=16 x 128) @ Ws^T, A-fragments direct from global (L1-hot)
    for (int k0 = 0; k0 < C_; k0 += 32) {
        half8 a[G_];
        #pragma unroll
        for (int g = 0; g < G_; ++g) {
            const float* p = x + (size_t)col * (N_ * C_) + (size_t)(n0 + g) * C_ + k0 + quad * 8;
            const float4 x0 = *(const float4*)p;
            const float4 x1 = *(const float4*)(p + 4);
            a[g] = (half8){(_Float16)x0.x, (_Float16)x0.y, (_Float16)x0.z, (_Float16)x0.w,
                           (_Float16)x1.x, (_Float16)x1.y, (_Float16)x1.z, (_Float16)x1.w};
        }
        #pragma unroll
        for (int t = 0; t < 2; ++t) {
            half8 b;
            if (WF16) {
                b = ((const half8*)WsP)[((w * 2 + t) * 4 + (k0 >> 5)) * 64 + lane];
            } else {
                const float* p = (const float*)WsP + (size_t)(o0 + t * 16 + col) * C_ + k0 + quad * 8;
                const float4 w0 = *(const float4*)p;
                const float4 w1 = *(const float4*)(p + 4);
                b = (half8){(_Float16)w0.x, (_Float16)w0.y, (_Float16)w0.z, (_Float16)w0.w,
                            (_Float16)w1.x, (_Float16)w1.y, (_Float16)w1.z, (_Float16)w1.w};
            }
            #pragma unroll
            for (int g = 0; g < G_; ++g)
                accS[g][t] = __builtin_amdgcn_mfma_f32_16x16x32_f16(a[g], b, accS[g][t], 0, 0, 0);
        }
    }

    // ---------------- epilogue: out = elu(conv + bc) + skip + bs ----------------
    float bcv[2], bsv[2];
    #pragma unroll
    for (int t = 0; t < 2; ++t) {
        bcv[t] = bc[o0 + t * 16 + col];
        bsv[t] = bs[o0 + t * 16 + col];
    }
    #pragma unroll
    for (int g = 0; g < G_; ++g) {
        const int n = n0 + g;
        #pragma unroll
        for (int t = 0; t < 2; ++t) {
            const int o = o0 + t * 16 + col;
            #pragma unroll
            for (int r = 0; r < 4; ++r) {
                const int m = quad * 4 + r;     // C/D: row = (lane>>4)*4 + reg
                const float z = elu_f(accC[g][t][r] + bcv[t]);
                out[((size_t)m * N_ + n) * C_ + o] = z + accS[g][t][r] + bsv[t];
            }
        }
    }
}

extern "C" void kernel_launch(void* const* d_in, const int* in_sizes, int n_in,
                              void* d_out, int out_size, void* d_ws, size_t ws_size,
                              hipStream_t stream) {
    const float* x   = (const float*)d_in[0];
    const int*   idx = (const int*)  d_in[1];
    const float* P   = (const float*)d_in[2];
    const float* Wc  = (const float*)d_in[3];
    const float* bc  = (const float*)d_in[4];
    const float* Ws  = (const float*)d_in[5];
    const float* bs  = (const float*)d_in[6];
    float* out = (float*)d_out;

    const size_t wc_halfs = (size_t)8 * 36 * 64 * 8;   // 147456
    const size_t ws_halfs = (size_t)8 * 4 * 64 * 8;    // 16384
    const size_t need = (wc_halfs + ws_halfs) * sizeof(_Float16);

    if (ws_size >= need) {
        _Float16* WcF = (_Float16*)d_ws;
        _Float16* WsF = WcF + wc_halfs;
        build_wfrag<<<dim3(576), dim3(256), 0, stream>>>(Wc, Ws, WcF, WsF);
        hipFuncSetAttribute((const void*)paiconv_mfma<true>,
                            hipFuncAttributeMaxDynamicSharedMemorySize, LDS_BYTES);
        paiconv_mfma<true><<<dim3(N_ / G_), dim3(256), LDS_BYTES, stream>>>(
            x, idx, P, WcF, bc, WsF, bs, out);
    } else {
        hipFuncSetAttribute((const void*)paiconv_mfma<false>,
                            hipFuncAttributeMaxDynamicSharedMemorySize, LDS_BYTES);
        paiconv_mfma<false><<<dim3(N_ / G_), dim3(256), LDS_BYTES, stream>>>(
            x, idx, P, Wc, bc, Ws, bs, out);
    }
}